// Round 1
// 201.530 us; speedup vs baseline: 1.0270x; 1.0270x over previous
//
#include <hip/hip_runtime.h>

#define B_ 64
#define T_ 512
#define D_ 768
#define K_ 21
#define NCHUNK 32    // chunks: c covers t in [c*16, c*16+16), chunk 0 starts at t=1
#define GSTRIDE 448  // padded 21*21
#define LOG21 3.0445224377234229965f
#define WSTRIDE 776  // W LDS row stride (halves), mult of 8
#define ASTRIDE 136  // A LDS row stride (halves), mult of 8

// wave-internal LDS ordering (lanes of one wave run in lockstep; only the
// LDS pipe needs draining between cross-lane write->read)
#define WAVE_SYNC() asm volatile("s_waitcnt lgkmcnt(0)" ::: "memory")

using f16x8 = __attribute__((ext_vector_type(8))) _Float16;
using h16x4 = __attribute__((ext_vector_type(4))) _Float16;
using f32x4 = __attribute__((ext_vector_type(4))) float;

// ---------------- Kernel 1: logits GEMM + fused per-chunk transfer products ---
// Block = 64 rows (one batch owns 8 consecutive blocks), 256 thr (4 waves x 16
// rows). After the GEMM, wave w's output rows are exactly the 16 timesteps of
// chunk (bx&7)*4+w, so each wave computes its chunk's normalized transfer-
// matrix product G_c in-place (LDS overlay on the dead A double-buffer).
// G==nullptr -> GEMM only (fallback path).
__global__ __launch_bounds__(256, 2) void proj_chunk_kernel(
    const float* __restrict__ A,
    const float* __restrict__ W,
    const float* __restrict__ bias,
    const int*   __restrict__ mask,
    const float* __restrict__ trans,
    float* __restrict__ out,            // d_out: [0]=loss, [1..]=logits
    float* __restrict__ G,
    float* __restrict__ SC,
    int*   __restrict__ cnt)
{
    __shared__ _Float16 Wh[K_ * WSTRIDE];     // 32592 B
    __shared__ _Float16 Ah[2][64 * ASTRIDE];  // 34816 B (reused post-GEMM)
    __shared__ float    sET[441];             // exp(transitions)
    const int tid  = threadIdx.x;
    const int lane = tid & 63;
    const int w    = tid >> 6;
    const int m    = lane & 15;
    const int quad = lane >> 4;
    const size_t row0 = (size_t)blockIdx.x * 64;
    const bool gmode = (G != nullptr);

    if (gmode && blockIdx.x == 0 && tid == 0) *cnt = 0;  // arms kernel 2's arrival counter

    const int b     = blockIdx.x >> 3;
    const int chunk = ((blockIdx.x & 7) << 2) + w;       // 0..31
    const int t0    = chunk * 16;

    // early mask load -> wave-uniform 16-bit step mask
    unsigned int mbits = 0;
    if (gmode) {
        const int mv = (lane < 16) ? mask[b * T_ + t0 + lane] : 0;
        const unsigned long long mb = __ballot(mv != 0);
        mbits = (unsigned int)(mb & 0xFFFFull);
        if (chunk == 0) mbits &= ~1u;   // t=0 is the init state, not a step
    }

    // stage W f32->f16 (coalesced) + exp(trans)
    {
        const float4* Wg = (const float4*)W;
        for (int i = tid; i < K_ * D_ / 4; i += 256) {
            const float4 v = Wg[i];
            const int fi = i * 4;
            const int r = fi / D_;
            const int c = fi - r * D_;
            h16x4 h;
            h[0] = (_Float16)v.x; h[1] = (_Float16)v.y;
            h[2] = (_Float16)v.z; h[3] = (_Float16)v.w;
            *(h16x4*)(&Wh[r * WSTRIDE + c]) = h;
        }
    }
    for (int i = tid; i < 441; i += 256) sET[i] = __expf(trans[i]);

    // stage A tile 0 (coalesced: 8 float4/thread)
    float4 pf[8];
    #pragma unroll
    for (int j = 0; j < 8; ++j) {
        const int i = tid + j * 256;
        const int r = i >> 5, c4 = i & 31;
        pf[j] = *(const float4*)(A + (row0 + r) * D_ + c4 * 4);
    }
    #pragma unroll
    for (int j = 0; j < 8; ++j) {
        const int i = tid + j * 256;
        const int r = i >> 5, c4 = i & 31;
        h16x4 h;
        h[0] = (_Float16)pf[j].x; h[1] = (_Float16)pf[j].y;
        h[2] = (_Float16)pf[j].z; h[3] = (_Float16)pf[j].w;
        *(h16x4*)(&Ah[0][r * ASTRIDE + c4 * 4]) = h;
    }
    __syncthreads();

    f32x4 acc0 = {0.f, 0.f, 0.f, 0.f};
    f32x4 acc1 = {0.f, 0.f, 0.f, 0.f};
    const int n1 = (16 + m < K_) ? 16 + m : K_ - 1;

    for (int kt = 0; kt < 6; ++kt) {
        if (kt < 5) {
            #pragma unroll
            for (int j = 0; j < 8; ++j) {
                const int i = tid + j * 256;
                const int r = i >> 5, c4 = i & 31;
                pf[j] = *(const float4*)(A + (row0 + r) * D_ + (kt + 1) * 128 + c4 * 4);
            }
        }
        const _Float16* Ab = Ah[kt & 1];
        #pragma unroll
        for (int s = 0; s < 4; ++s) {
            const f16x8 af = *(const f16x8*)(&Ab[(w * 16 + m) * ASTRIDE + s * 32 + quad * 8]);
            const f16x8 bf = *(const f16x8*)(&Wh[m * WSTRIDE + kt * 128 + s * 32 + quad * 8]);
            const f16x8 cf = *(const f16x8*)(&Wh[n1 * WSTRIDE + kt * 128 + s * 32 + quad * 8]);
            acc0 = __builtin_amdgcn_mfma_f32_16x16x32_f16(af, bf, acc0, 0, 0, 0);
            acc1 = __builtin_amdgcn_mfma_f32_16x16x32_f16(af, cf, acc1, 0, 0, 0);
        }
        if (kt < 5) {
            _Float16* Aw = Ah[(kt + 1) & 1];
            #pragma unroll
            for (int j = 0; j < 8; ++j) {
                const int i = tid + j * 256;
                const int r = i >> 5, c4 = i & 31;
                h16x4 h;
                h[0] = (_Float16)pf[j].x; h[1] = (_Float16)pf[j].y;
                h[2] = (_Float16)pf[j].z; h[3] = (_Float16)pf[j].w;
                *(h16x4*)(&Aw[r * ASTRIDE + c4 * 4]) = h;
            }
        }
        __syncthreads();
    }

    // per-wave overlay on dead Ah: M0 | M1 | em(16x21) | smx(16)  (1280 f/wave)
    float* const cb  = reinterpret_cast<float*>(&Ah[0][0]) + w * 1280;
    float* const M0p = cb;
    float* const M1p = cb + 441;
    float* const em  = cb + 882;
    float* const smx = cb + 1218;

    // epilogue (C layout verified: col=lane&15, row=quad*4+reg)
    const size_t rbase = row0 + w * 16 + quad * 4;
    {
        const float bb = bias[m];
        float* o = out + 1 + rbase * K_ + m;
        #pragma unroll
        for (int r = 0; r < 4; ++r) {
            const float v = acc0[r] + bb;
            o[(size_t)r * K_] = v;
            if (gmode) em[(quad * 4 + r) * K_ + m] = v;
        }
    }
    const int col2 = 16 + m;
    if (col2 < K_) {
        const float bb = bias[col2];
        float* o = out + 1 + rbase * K_ + col2;
        #pragma unroll
        for (int r = 0; r < 4; ++r) {
            const float v = acc1[r] + bb;
            o[(size_t)r * K_] = v;
            if (gmode) em[(quad * 4 + r) * K_ + col2] = v;
        }
    }
    if (!gmode) return;
    WAVE_SYNC();

    // per-step max (lanes 0..15 own one timestep each)
    if (lane < 16) {
        float mx = -1e30f;
        #pragma unroll
        for (int j = 0; j < K_; ++j) mx = fmaxf(mx, em[lane * K_ + j]);
        smx[lane] = mx;
    }
    WAVE_SYNC();
    // normalized emissions: exp(x - mx)/21
    #pragma unroll
    for (int ii = 0; ii < 6; ++ii) {
        const int idx = lane + ii * 64;
        if (idx < 336) em[idx] = __expf(em[idx] - smx[idx / K_]) * (1.0f / 21.0f);
    }

    // lane l<63 -> (row i=l/3, colgroup jg=l%3) owns 7 outputs; ET cols in regs
    const int  i_  = lane / 3;
    const int  jg  = lane - i_ * 3;
    const bool act = lane < 63;
    float ETc[K_ * 7];
    if (act) {
        #pragma unroll
        for (int mm = 0; mm < K_; ++mm) {
            #pragma unroll
            for (int q = 0; q < 7; ++q)
                ETc[mm * 7 + q] = sET[mm * K_ + jg * 7 + q];
        }
    }
    for (int idx = lane; idx < 441; idx += 64)
        M0p[idx] = (idx % 22 == 0) ? 1.0f : 0.0f;
    WAVE_SYNC();

    int cur = 0;
    for (int s = 0; s < 16; ++s) {
        if ((mbits >> s) & 1u) {              // wave-uniform
            const float* Mr = cur ? M1p : M0p;
            float*       Mw = cur ? M0p : M1p;
            if (act) {
                float facc[7] = {0.f,0.f,0.f,0.f,0.f,0.f,0.f};
                #pragma unroll
                for (int mm = 0; mm < K_; ++mm) {
                    const float lm = Mr[i_ * K_ + mm];
                    #pragma unroll
                    for (int q = 0; q < 7; ++q)
                        facc[q] = fmaf(lm, ETc[mm * 7 + q], facc[q]);
                }
                #pragma unroll
                for (int q = 0; q < 7; ++q)
                    Mw[i_ * K_ + jg * 7 + q] = facc[q] * em[s * K_ + jg * 7 + q];
            }
            WAVE_SYNC();                      // writes visible before next step's reads
            cur ^= 1;
        }
    }

    // scale sum over masked steps
    float scv = (lane < 16 && ((mbits >> lane) & 1u)) ? smx[lane] + LOG21 : 0.0f;
    #pragma unroll
    for (int off = 8; off >= 1; off >>= 1) scv += __shfl_xor(scv, off, 64);

    const float* Mf = cur ? M1p : M0p;
    float* Gc = G + (size_t)(b * NCHUNK + chunk) * GSTRIDE;
    for (int idx = lane; idx < 441; idx += 64) Gc[idx] = Mf[idx];
    if (lane == 0) SC[b * NCHUNK + chunk] = scv;
}

// ---------------- Kernel 2: scan + gold score + fused final reduction ---------
// 4 waves stage G (56KB) + masks; wave 0 runs the 32-step scan with shuffle-
// broadcast v and lane0-renorm; waves 1-3 compute the gold-path score. Last
// block to arrive (device-scope counter, zeroed by kernel 1) reduces ll/ms
// and writes the loss — no separate fin launch.
__global__ __launch_bounds__(256) void scan_fin_kernel(
    const float* __restrict__ outF,
    const int*   __restrict__ tags,
    const int*   __restrict__ mask,
    const float* __restrict__ trans,
    const float* __restrict__ startT,
    const float* __restrict__ endT,
    const float* __restrict__ G,
    const float* __restrict__ SC,
    float* __restrict__ ll,
    float* __restrict__ msum,
    int*   __restrict__ cnt,
    float* __restrict__ outW)
{
    __shared__ float sG[NCHUNK * GSTRIDE];   // 57344 B
    __shared__ float sm[T_];
    __shared__ int   st[T_];
    __shared__ float part[8];
    __shared__ int   lastF;
    const int tid = threadIdx.x;
    const int lane = tid & 63;
    const int w = tid >> 6;
    const int b = blockIdx.x;
    const float* lg = outF + 1 + (size_t)b * T_ * K_;

    {
        const float4* Gf4 = (const float4*)(G + (size_t)b * NCHUNK * GSTRIDE);
        float4* dst = (float4*)sG;
        for (int i = tid; i < NCHUNK * GSTRIDE / 4; i += 256) dst[i] = Gf4[i];
    }
    for (int t = tid; t < T_; t += 256) {
        sm[t] = (float)mask[b * T_ + t];
        st[t] = tags[b * T_ + t];
    }
    __syncthreads();

    float logZ = 0.0f;
    if (w == 0) {
        const float scv = (lane < NCHUNK) ? SC[b * NCHUNK + lane] : 0.0f;
        const int jc = min(lane, K_ - 1);
        float v = (lane < K_) ? __expf(startT[lane] + lg[lane]) : 0.0f;
        float C = 0.0f;
        for (int c = 0; c < NCHUNK; ++c) {
            const float* Gc = sG + c * GSTRIDE;
            float a0 = 0.f, a1 = 0.f, a2 = 0.f;
            #pragma unroll
            for (int i = 0; i < K_; i += 3) {
                a0 = fmaf(__shfl(v, i,     64), Gc[i * K_ + jc],       a0);
                a1 = fmaf(__shfl(v, i + 1, 64), Gc[(i + 1) * K_ + jc], a1);
                a2 = fmaf(__shfl(v, i + 2, 64), Gc[(i + 2) * K_ + jc], a2);
            }
            const float s = a0 + a1 + a2;
            const float s0 = __shfl(s, 0, 64);     // >0 always (all-positive G)
            v = s / s0;
            C += __logf(s0) + __shfl(scv, c, 64);
        }
        float term = (lane < K_) ? v * __expf(endT[lane]) : 0.0f;
        #pragma unroll
        for (int off = 16; off >= 1; off >>= 1) term += __shfl_xor(term, off, 64);
        term += __shfl_xor(term, 32, 64);
        logZ = C + __logf(term);
    } else {
        float sc = 0.0f, ms = 0.0f;
        for (int t = tid - 64; t < T_; t += 192) {
            const float mt = sm[t];
            ms += mt;
            if (t < T_ - 1) {
                const int ct = st[t], nt2 = st[t + 1];
                sc += trans[ct * K_ + nt2] * sm[t + 1] + lg[t * K_ + ct] * mt;
            }
        }
        #pragma unroll
        for (int off = 32; off >= 1; off >>= 1) {
            sc += __shfl_xor(sc, off, 64);
            ms += __shfl_xor(ms, off, 64);
        }
        if (lane == 0) { part[w] = sc; part[4 + w] = ms; }
    }
    __syncthreads();

    if (tid == 0) {
        float sc = part[1] + part[2] + part[3];
        float ms = part[5] + part[6] + part[7];
        const int lastIdx = (int)ms - 1;
        const int lastTag = st[lastIdx];
        sc += startT[st[0]] + endT[lastTag] + lg[(T_ - 1) * K_ + lastTag] * sm[T_ - 1];
        ll[b]   = sc - logZ;
        msum[b] = ms;
        __threadfence();                          // release our ll/ms
        lastF = (atomicAdd(cnt, 1) == B_ - 1) ? 1 : 0;
    }
    __syncthreads();

    if (lastF != 0 && w == 0) {
        __threadfence();                          // acquire others' ll/ms
        float l  = ll[lane];
        float mm = msum[lane];
        #pragma unroll
        for (int off = 32; off >= 1; off >>= 1) {
            l  += __shfl_xor(l,  off, 64);
            mm += __shfl_xor(mm, off, 64);
        }
        if (lane == 0) outW[0] = -l / mm;
    }
}

// ---------------- Kernel 3 (fallback only): loss = -sum(ll)/sum(mask) ---------
__global__ __launch_bounds__(64) void fin_kernel(
    const float* __restrict__ ll, const float* __restrict__ msum,
    float* __restrict__ outF)
{
    const int lane = threadIdx.x;
    float l = ll[lane];
    float m = msum[lane];
    #pragma unroll
    for (int off = 32; off >= 1; off >>= 1) {
        l += __shfl_xor(l, off, 64);
        m += __shfl_xor(m, off, 64);
    }
    if (lane == 0) outF[0] = -l / m;
}

// ---------------- Fallback (ws too small): sequential CRF ----------------------
__global__ __launch_bounds__(64) void crf_kernel(
    const float* __restrict__ outF,
    const int*   __restrict__ tags,
    const int*   __restrict__ mask,
    const float* __restrict__ trans,
    const float* __restrict__ startT,
    const float* __restrict__ endT,
    float* __restrict__ ws)
{
    __shared__ float se[T_ * K_];
    __shared__ float sm[T_];
    __shared__ int   st[T_];
    const int b = blockIdx.x;
    const int lane = threadIdx.x;

    const float* lg = outF + 1 + (size_t)b * T_ * K_;
    for (int i = lane; i < T_ * K_; i += 64) se[i] = lg[i];
    for (int t = lane; t < T_; t += 64) {
        sm[t] = (float)mask[b * T_ + t];
        st[t] = tags[b * T_ + t];
    }
    __syncthreads();

    const int jc = lane < K_ ? lane : K_ - 1;
    float ET[K_];
    #pragma unroll
    for (int i = 0; i < K_; ++i) ET[i] = __expf(trans[i * K_ + jc]);

    float a0   = startT[jc] + se[jc];
    float r0   = __shfl(a0, 0, 64);
    float aRel = a0 - r0;
    float C    = r0;

    for (int t = 1; t < T_; ++t) {
        if (sm[t] != 0.0f) {
            float e = __expf(aRel);
            float s = 0.0f;
            #pragma unroll
            for (int i = 0; i < K_; ++i)
                s = fmaf(__shfl(e, i, 64), ET[i], s);
            float raw = __logf(s) + se[t * K_ + jc];
            float rr  = __shfl(raw, 0, 64);
            aRel = raw - rr;
            C   += rr;
        }
    }

    float contrib = (lane < K_) ? __expf(aRel + endT[jc]) : 0.0f;
    #pragma unroll
    for (int off = 32; off >= 1; off >>= 1) contrib += __shfl_xor(contrib, off, 64);
    const float logZ = C + __logf(contrib);

    float sc = 0.0f, ms = 0.0f;
    for (int t = lane; t < T_; t += 64) {
        const float mt = sm[t];
        ms += mt;
        if (t < T_ - 1) {
            const int ct = st[t], nt2 = st[t + 1];
            sc += trans[ct * K_ + nt2] * sm[t + 1] + se[t * K_ + ct] * mt;
        }
    }
    #pragma unroll
    for (int off = 32; off >= 1; off >>= 1) {
        sc += __shfl_xor(sc, off, 64);
        ms += __shfl_xor(ms, off, 64);
    }
    if (lane == 0) {
        const int lastIdx = (int)ms - 1;
        const int lastTag = st[lastIdx];
        sc += startT[st[0]] + endT[lastTag] + se[(T_ - 1) * K_ + lastTag] * sm[T_ - 1];
        ws[b]      = sc - logZ;
        ws[B_ + b] = ms;
    }
}

extern "C" void kernel_launch(void* const* d_in, const int* in_sizes, int n_in,
                              void* d_out, int out_size, void* d_ws, size_t ws_size,
                              hipStream_t stream) {
    const float* A     = (const float*)d_in[0];   // vectors [64,512,768] f32
    const int*   tags  = (const int*)  d_in[1];   // targets [64,512] i32
    const int*   mask  = (const int*)  d_in[2];   // mask    [64,512] i32
    const float* W     = (const float*)d_in[3];   // W [21,768] f32
    const float* bias  = (const float*)d_in[4];   // b [21]
    const float* trans = (const float*)d_in[5];   // transitions [21,21]
    const float* stT   = (const float*)d_in[6];   // start_trans [21]
    const float* enT   = (const float*)d_in[7];   // end_trans [21]
    float* outF = (float*)d_out;
    float* ws   = (float*)d_ws;

    // ws layout (floats): G[64*32*448] | SC[64*32] | ll[64] | ms[64] | cnt(int)
    const size_t gFloats = (size_t)B_ * NCHUNK * GSTRIDE;
    const size_t scOff   = gFloats;
    const size_t llOff   = scOff + (size_t)B_ * NCHUNK;
    const size_t msOff   = llOff + B_;
    const size_t cntOff  = msOff + B_;
    const size_t needBytes = cntOff * sizeof(float) + sizeof(int);

    if (ws_size >= needBytes) {
        float* G   = ws;
        float* SC  = ws + scOff;
        float* llp = ws + llOff;
        float* msv = ws + msOff;
        int*   cnt = (int*)(ws + cntOff);
        proj_chunk_kernel<<<512, 256, 0, stream>>>(A, W, bias, mask, trans, outF, G, SC, cnt);
        scan_fin_kernel<<<B_, 256, 0, stream>>>(outF, tags, mask, trans, stT, enT, G, SC, llp, msv, cnt, outF);
    } else {
        proj_chunk_kernel<<<512, 256, 0, stream>>>(A, W, bias, mask, trans, outF, nullptr, nullptr, nullptr);
        crf_kernel<<<B_, 64, 0, stream>>>(outF, tags, mask, trans, stT, enT, ws);
        fin_kernel<<<1, 64, 0, stream>>>(ws, ws + B_, outF);
    }
}